// Round 7
// baseline (28261.807 us; speedup 1.0000x reference)
//
#include <hip/hip_runtime.h>

#define NN 8192
#define DD 32
// stagger-padded LDS index: +4 floats of pad per 16 (keeps 16B alignment)
#define SIDX(c) ((c) + 4 * ((c) >> 4))

constexpr float kEps   = 0.1f;
constexpr float kStab  = 1e-8f;
constexpr float kMass  = 1.0f / 8192.0f;     // mu = nu = 1/n
constexpr float kInvSc = 1.0f / 256.0f;      // K stored as fp8 of 256*K
constexpr float kLnSc  = 5.545177444479562f; // ln(256)

typedef float v2f __attribute__((ext_vector_type(2)));

__device__ inline void cvt8x4(unsigned int w, float* out) {
    v2f lo = __builtin_amdgcn_cvt_pk_f32_fp8(w, false);
    v2f hi = __builtin_amdgcn_cvt_pk_f32_fp8(w, true);
    out[0] = lo.x; out[1] = lo.y; out[2] = hi.x; out[3] = hi.y;
}
__device__ inline void cvt16(uint4 kk, float* f) {
    cvt8x4(kk.x, f); cvt8x4(kk.y, f + 4); cvt8x4(kk.z, f + 8); cvt8x4(kk.w, f + 12);
}
__device__ inline unsigned int pack8x4(float a, float b, float c, float d) {
    int v = 0;
    v = __builtin_amdgcn_cvt_pk_fp8_f32(a, b, v, false);
    v = __builtin_amdgcn_cvt_pk_fp8_f32(c, d, v, true);
    return (unsigned int)v;
}
__device__ inline float xform(float raw) {
    return kMass * __builtin_amdgcn_rcpf(fmaf(raw, kInvSc, kStab));
}

// -------------------------------- build K8 = fp8(256*exp(-cost/eps)), z = transport
__global__ __launch_bounds__(256) void sk_build_k(const float* __restrict__ src,
                                                  const float* __restrict__ tgt,
                                                  unsigned char* __restrict__ K8) {
    const int z = blockIdx.z;
    const float* X = src; const float* Y = tgt;
    if (z == 1) Y = src; else if (z == 2) X = tgt;
    unsigned char* K = K8 + (size_t)z * NN * NN;

    __shared__ float xs[DD * 64];
    __shared__ float ys[DD * 64];
    __shared__ float sx[64], sy[64];
    const int t  = threadIdx.x;
    const int r0 = blockIdx.y * 64, c0 = blockIdx.x * 64;

    for (int idx = t; idx < DD * 64; idx += 256) {
        int d = idx >> 6, row = idx & 63;
        xs[idx] = X[(size_t)(r0 + row) * DD + d];
        ys[idx] = Y[(size_t)(c0 + row) * DD + d];
    }
    __syncthreads();
    if (t < 64) {
        float s = 0.f;
        for (int d = 0; d < DD; d++) { float v = xs[d * 64 + t]; s = fmaf(v, v, s); }
        sx[t] = s;
    } else if (t < 128) {
        int q = t - 64; float s = 0.f;
        for (int d = 0; d < DD; d++) { float v = ys[d * 64 + q]; s = fmaf(v, v, s); }
        sy[q] = s;
    }
    __syncthreads();

    const int tr = t >> 4, tc = t & 15;
    float acc[4][4] = {};
    for (int d = 0; d < DD; d++) {
        const float4 xa = *reinterpret_cast<const float4*>(&xs[d * 64 + 4 * tr]);
        const float4 yb = *reinterpret_cast<const float4*>(&ys[d * 64 + 4 * tc]);
        const float xav[4] = {xa.x, xa.y, xa.z, xa.w};
        const float ybv[4] = {yb.x, yb.y, yb.z, yb.w};
#pragma unroll
        for (int a = 0; a < 4; a++)
#pragma unroll
            for (int b = 0; b < 4; b++) acc[a][b] = fmaf(xav[a], ybv[b], acc[a][b]);
    }
#pragma unroll
    for (int a = 0; a < 4; a++) {
        const int r = r0 + 4 * tr + a;
        const float sxa = sx[4 * tr + a];
        float e[4];
#pragma unroll
        for (int b = 0; b < 4; b++) {
            float cost = sxa + sy[4 * tc + b] - 2.0f * acc[a][b];
            cost = fmaxf(cost, 0.0f);
            e[b] = __expf(fmaf(-10.0f, cost, kLnSc));   // 256 * exp(-cost/eps)
        }
        *reinterpret_cast<unsigned int*>(&K[(size_t)r * NN + c0 + 4 * tc]) =
            pack8x4(e[0], e[1], e[2], e[3]);
    }
}

// -------------------------------- fused Sinkhorn pass: ONE read of K per iteration
// Given rc (=256*K^T u_prev): v = xform(rc) [registers]; per row i: u_i = m/(K_i v);
// col-partials colacc += u_i * K_i [registers]; flush to scratch[band] at end.
// Block spans the full 8192-col row width: wave w owns cols [2048w,2048w+1024) and
// [2048w+1024, 2048w+2048); lane owns 32 fixed cols. 32 rows/block, grid (256,1,3).
// mode: 0 = normal, 1 = prepass (v=1, colacc uses u=1), 2 = final (skip col part).
__global__ __launch_bounds__(256, 3) void sk_pass(const unsigned char* __restrict__ K8,
                                                  const float* __restrict__ rc_in,
                                                  float* __restrict__ scratch,
                                                  float* __restrict__ u_arr,
                                                  int bands, int mode) {
    __shared__ float part[2][16];
    const int z = blockIdx.z, b = blockIdx.x, t = threadIdx.x;
    const int lane = t & 63, w = t >> 6;
    const unsigned char* K = K8 + (size_t)z * NN * NN;
    const int cA = 2048 * w + 16 * lane;
    const int cB = cA + 1024;

    float vA[16], vB[16];
    if (mode == 1) {
#pragma unroll
        for (int j = 0; j < 16; j++) { vA[j] = 1.0f; vB[j] = 1.0f; }
    } else {
        const float* rc = rc_in + z * NN;
#pragma unroll
        for (int g4 = 0; g4 < 4; g4++) {
            float4 ra = *reinterpret_cast<const float4*>(rc + cA + 4 * g4);
            float4 rb = *reinterpret_cast<const float4*>(rc + cB + 4 * g4);
            vA[4 * g4 + 0] = xform(ra.x); vA[4 * g4 + 1] = xform(ra.y);
            vA[4 * g4 + 2] = xform(ra.z); vA[4 * g4 + 3] = xform(ra.w);
            vB[4 * g4 + 0] = xform(rb.x); vB[4 * g4 + 1] = xform(rb.y);
            vB[4 * g4 + 2] = xform(rb.z); vB[4 * g4 + 3] = xform(rb.w);
        }
    }

    float colA[16] = {}, colB[16] = {};
    const int r0 = b * 32;

    for (int g = 0; g < 8; g++) {
        const int rg = r0 + 4 * g;
        uint4 kA[4], kB[4];
#pragma unroll
        for (int r = 0; r < 4; r++) {
            const unsigned char* rowp = K + (size_t)(rg + r) * NN;
            kA[r] = *reinterpret_cast<const uint4*>(rowp + cA);
            kB[r] = *reinterpret_cast<const uint4*>(rowp + cB);
        }
        float p0 = 0.f, p1 = 0.f, p2 = 0.f, p3 = 0.f;
        {
            float f[16];
            cvt16(kA[0], f);
#pragma unroll
            for (int j = 0; j < 16; j++) p0 = fmaf(f[j], vA[j], p0);
            cvt16(kB[0], f);
#pragma unroll
            for (int j = 0; j < 16; j++) p0 = fmaf(f[j], vB[j], p0);
            cvt16(kA[1], f);
#pragma unroll
            for (int j = 0; j < 16; j++) p1 = fmaf(f[j], vA[j], p1);
            cvt16(kB[1], f);
#pragma unroll
            for (int j = 0; j < 16; j++) p1 = fmaf(f[j], vB[j], p1);
            cvt16(kA[2], f);
#pragma unroll
            for (int j = 0; j < 16; j++) p2 = fmaf(f[j], vA[j], p2);
            cvt16(kB[2], f);
#pragma unroll
            for (int j = 0; j < 16; j++) p2 = fmaf(f[j], vB[j], p2);
            cvt16(kA[3], f);
#pragma unroll
            for (int j = 0; j < 16; j++) p3 = fmaf(f[j], vA[j], p3);
            cvt16(kB[3], f);
#pragma unroll
            for (int j = 0; j < 16; j++) p3 = fmaf(f[j], vB[j], p3);
        }
#pragma unroll
        for (int off = 32; off > 0; off >>= 1) {
            p0 += __shfl_xor(p0, off); p1 += __shfl_xor(p1, off);
            p2 += __shfl_xor(p2, off); p3 += __shfl_xor(p3, off);
        }
        const int slot = g & 1;
        if (lane == 0) {
            part[slot][4 * w + 0] = p0; part[slot][4 * w + 1] = p1;
            part[slot][4 * w + 2] = p2; part[slot][4 * w + 3] = p3;
        }
        __syncthreads();
        if (t < 4) {
            const float s = part[slot][t] + part[slot][4 + t] +
                            part[slot][8 + t] + part[slot][12 + t];
            u_arr[z * NN + rg + t] = kMass / (s * kInvSc + kStab);
        }
        if (mode != 2) {
            float u4[4];
#pragma unroll
            for (int r = 0; r < 4; r++) {
                const float s = part[slot][r] + part[slot][4 + r] +
                                part[slot][8 + r] + part[slot][12 + r];
                u4[r] = (mode == 1)
                          ? 1.0f
                          : kMass * __builtin_amdgcn_rcpf(fmaf(s, kInvSc, kStab));
            }
#pragma unroll
            for (int r = 0; r < 4; r++) {
                float f[16];
                cvt16(kA[r], f);
#pragma unroll
                for (int j = 0; j < 16; j++) colA[j] = fmaf(f[j], u4[r], colA[j]);
                cvt16(kB[r], f);
#pragma unroll
                for (int j = 0; j < 16; j++) colB[j] = fmaf(f[j], u4[r], colB[j]);
            }
        }
    }
    if (mode != 2) {
        float* sc = scratch + ((size_t)z * bands + (b & (bands - 1))) * NN;
        if (bands == 256) {   // one block per band: plain overwrite, no zeroing
#pragma unroll
            for (int g4 = 0; g4 < 4; g4++) {
                float4 a = {colA[4 * g4], colA[4 * g4 + 1],
                            colA[4 * g4 + 2], colA[4 * g4 + 3]};
                float4 bb = {colB[4 * g4], colB[4 * g4 + 1],
                             colB[4 * g4 + 2], colB[4 * g4 + 3]};
                *reinterpret_cast<float4*>(sc + cA + 4 * g4) = a;
                *reinterpret_cast<float4*>(sc + cB + 4 * g4) = bb;
            }
        } else {              // fallback: shared bands, atomic accumulate
#pragma unroll
            for (int j = 0; j < 16; j++) {
                atomicAdd(sc + cA + j, colA[j]);
                atomicAdd(sc + cB + j, colB[j]);
            }
        }
    }
}

// -------------------------------- rc_out[col] = sum over bands of scratch
__global__ __launch_bounds__(256) void sk_reduce(float* __restrict__ scratch,
                                                 float* __restrict__ rc_out,
                                                 int bands) {
    const int z = blockIdx.z;
    const int col = blockIdx.x * 256 + threadIdx.x;
    float* base = scratch + (size_t)z * bands * NN + col;
    float s = 0.f;
#pragma unroll 8
    for (int b = 0; b < bands; b++) s += base[(size_t)b * NN];
    if (bands != 256) {   // atomic fallback path: re-zero for next pass
        for (int b = 0; b < bands; b++) base[(size_t)b * NN] = 0.f;
    }
    rc_out[z * NN + col] = s;
}

// -------------------------------- w[z] = sum u_i K_ij v_j cost_ij, cost = -eps*ln(K)
__global__ __launch_bounds__(256) void sk_wsum(const unsigned char* __restrict__ K8,
                                               const float* __restrict__ rc_v,
                                               const float* __restrict__ u_arr,
                                               double* __restrict__ acc_out) {
    __shared__ float vs[10240];
    __shared__ double wred[4];
    const int t = threadIdx.x;
    const int z = blockIdx.z;
    const unsigned char* K = K8 + (size_t)z * NN * NN;
#pragma unroll
    for (int qq = 0; qq < 8; qq++) {
        const int j = 4 * t + 1024 * qq;
        float4 r = *reinterpret_cast<const float4*>(rc_v + z * NN + j);
        float4 g = {xform(r.x), xform(r.y), xform(r.z), xform(r.w)};
        *reinterpret_cast<float4*>(&vs[SIDX(j)]) = g;
    }
    __syncthreads();

    const int lane = t & 63, w = t >> 6;
    const int rbase = blockIdx.x * 32 + 8 * w;
    float pr[8] = {};
    const unsigned char* rp = K + (size_t)rbase * NN + 16 * lane;
    for (int s = 0; s < 8; s++) {
        const float* vp = &vs[20 * lane + 1280 * s];
        float vv[16];
#pragma unroll
        for (int g = 0; g < 4; g++) {
            float4 v4 = *reinterpret_cast<const float4*>(vp + 4 * g);
            vv[4 * g] = v4.x; vv[4 * g + 1] = v4.y;
            vv[4 * g + 2] = v4.z; vv[4 * g + 3] = v4.w;
        }
        const unsigned char* ps = rp + 1024 * s;
#pragma unroll
        for (int r = 0; r < 8; r++) {
            uint4 kk = *reinterpret_cast<const uint4*>(ps + (size_t)r * NN);
            float f[16];
            cvt16(kk, f);
            float a = pr[r];
#pragma unroll
            for (int j = 0; j < 16; j++)
                a = fmaf(f[j] * vv[j], __logf(fmaxf(f[j], 1e-30f) * kInvSc), a);
            pr[r] = a;
        }
    }
    double lacc = 0.0;
#pragma unroll
    for (int r = 0; r < 8; r++)
        lacc += (double)(u_arr[z * NN + rbase + r] * pr[r]);
    lacc *= (double)kInvSc;
    for (int off = 32; off > 0; off >>= 1) lacc += __shfl_down(lacc, off);
    if (lane == 0) wred[w] = lacc;
    __syncthreads();
    if (t == 0) {
        double total = -(double)kEps * (wred[0] + wred[1] + wred[2] + wred[3]);
        atomicAdd(&acc_out[z], total);
    }
}

// ------------------------------------------------- combine
__global__ void sk_combine(const double* __restrict__ acc, float* __restrict__ out) {
    if (threadIdx.x == 0)
        out[0] = (float)((acc[0] - 0.5 * acc[1] - 0.5 * acc[2]) / 8192.0);
}

extern "C" void kernel_launch(void* const* d_in, const int* in_sizes, int n_in,
                              void* d_out, int out_size, void* d_ws, size_t ws_size,
                              hipStream_t stream) {
    const float* src = (const float*)d_in[0];
    const float* tgt = (const float*)d_in[1];
    float* out = (float*)d_out;
    char* ws = (char*)d_ws;

    // workspace layout: K (192 MB) | scratch (bands*96KB) | rc0 | rc1 | u | wacc
    const size_t fixed = 3ull * NN * NN + 9ull * NN * sizeof(float) + 64;
    int bands = 256;
    while (bands > 16 && fixed + 3ull * bands * NN * sizeof(float) > ws_size)
        bands >>= 1;

    unsigned char* K8 = (unsigned char*)ws;
    float* scratch = (float*)(ws + 3ull * NN * NN);
    float* rc0   = scratch + (size_t)3 * bands * NN;
    float* rc1   = rc0 + 3 * NN;
    float* u_arr = rc1 + 3 * NN;
    double* wacc = (double*)(u_arr + 3 * NN);
    float* rcs[2] = {rc0, rc1};

    hipMemsetAsync(wacc, 0, 3 * sizeof(double), stream);
    if (bands != 256)   // atomic fallback needs zeroed scratch
        hipMemsetAsync(scratch, 0, 3ull * bands * NN * sizeof(float), stream);

    sk_build_k<<<dim3(128, 128, 3), 256, 0, stream>>>(src, tgt, K8);

    // prepass: rc_1 = 256 * K^T 1  (column sums)
    sk_pass<<<dim3(256, 1, 3), 256, 0, stream>>>(K8, rc0, scratch, u_arr, bands, 1);
    sk_reduce<<<dim3(32, 1, 3), 256, 0, stream>>>(scratch, rcs[1], bands);

    for (int it = 1; it <= 100; it++) {
        const int mode = (it == 100) ? 2 : 0;
        sk_pass<<<dim3(256, 1, 3), 256, 0, stream>>>(K8, rcs[it & 1], scratch,
                                                     u_arr, bands, mode);
        if (it < 100)
            sk_reduce<<<dim3(32, 1, 3), 256, 0, stream>>>(scratch,
                                                          rcs[(it + 1) & 1], bands);
    }
    // pass 100 read rcs[0] (= 256*K^T u_99): v_100 = xform(rcs[0]); u_100 in u_arr
    sk_wsum<<<dim3(256, 1, 3), 256, 0, stream>>>(K8, rcs[0], u_arr, wacc);
    sk_combine<<<1, 64, 0, stream>>>(wacc, out);
}

// Round 8
// 9260.859 us; speedup vs baseline: 3.0517x; 3.0517x over previous
//
#include <hip/hip_runtime.h>

#define NN 8192
#define DD 32
// stagger-padded LDS index: +4 floats of pad per 16 (keeps 16B alignment)
#define SIDX(c) ((c) + 4 * ((c) >> 4))

constexpr float kEps   = 0.1f;
constexpr float kStab  = 1e-8f;
constexpr float kMass  = 1.0f / 8192.0f;     // mu = nu = 1/n
constexpr float kInvSc = 1.0f / 256.0f;      // K stored as fp8 of 256*K
constexpr float kLnSc  = 5.545177444479562f; // ln(256)

typedef float v2f __attribute__((ext_vector_type(2)));

__device__ inline void cvt8x4(unsigned int w, float* out) {
    v2f lo = __builtin_amdgcn_cvt_pk_f32_fp8(w, false);
    v2f hi = __builtin_amdgcn_cvt_pk_f32_fp8(w, true);
    out[0] = lo.x; out[1] = lo.y; out[2] = hi.x; out[3] = hi.y;
}
__device__ inline void cvt16(uint4 kk, float* f) {
    cvt8x4(kk.x, f); cvt8x4(kk.y, f + 4); cvt8x4(kk.z, f + 8); cvt8x4(kk.w, f + 12);
}
__device__ inline unsigned int pack8x4(float a, float b, float c, float d) {
    int v = 0;
    v = __builtin_amdgcn_cvt_pk_fp8_f32(a, b, v, false);
    v = __builtin_amdgcn_cvt_pk_fp8_f32(c, d, v, true);
    return (unsigned int)v;
}
__device__ inline float xform(float raw) {
    return kMass * __builtin_amdgcn_rcpf(fmaf(raw, kInvSc, kStab));
}

// -------------------------------- build K8 = fp8(256*exp(-cost/eps)), z = transport
__global__ __launch_bounds__(256) void sk_build_k(const float* __restrict__ src,
                                                  const float* __restrict__ tgt,
                                                  unsigned char* __restrict__ K8) {
    const int z = blockIdx.z;
    const float* X = src; const float* Y = tgt;
    if (z == 1) Y = src; else if (z == 2) X = tgt;
    unsigned char* K = K8 + (size_t)z * NN * NN;

    __shared__ float xs[DD * 64];
    __shared__ float ys[DD * 64];
    __shared__ float sx[64], sy[64];
    const int t  = threadIdx.x;
    const int r0 = blockIdx.y * 64, c0 = blockIdx.x * 64;

    for (int idx = t; idx < DD * 64; idx += 256) {
        int d = idx >> 6, row = idx & 63;
        xs[idx] = X[(size_t)(r0 + row) * DD + d];
        ys[idx] = Y[(size_t)(c0 + row) * DD + d];
    }
    __syncthreads();
    if (t < 64) {
        float s = 0.f;
        for (int d = 0; d < DD; d++) { float v = xs[d * 64 + t]; s = fmaf(v, v, s); }
        sx[t] = s;
    } else if (t < 128) {
        int q = t - 64; float s = 0.f;
        for (int d = 0; d < DD; d++) { float v = ys[d * 64 + q]; s = fmaf(v, v, s); }
        sy[q] = s;
    }
    __syncthreads();

    const int tr = t >> 4, tc = t & 15;
    float acc[4][4] = {};
    for (int d = 0; d < DD; d++) {
        const float4 xa = *reinterpret_cast<const float4*>(&xs[d * 64 + 4 * tr]);
        const float4 yb = *reinterpret_cast<const float4*>(&ys[d * 64 + 4 * tc]);
        const float xav[4] = {xa.x, xa.y, xa.z, xa.w};
        const float ybv[4] = {yb.x, yb.y, yb.z, yb.w};
#pragma unroll
        for (int a = 0; a < 4; a++)
#pragma unroll
            for (int b = 0; b < 4; b++) acc[a][b] = fmaf(xav[a], ybv[b], acc[a][b]);
    }
#pragma unroll
    for (int a = 0; a < 4; a++) {
        const int r = r0 + 4 * tr + a;
        const float sxa = sx[4 * tr + a];
        float e[4];
#pragma unroll
        for (int b = 0; b < 4; b++) {
            float cost = sxa + sy[4 * tc + b] - 2.0f * acc[a][b];
            cost = fmaxf(cost, 0.0f);
            e[b] = __expf(fmaf(-10.0f, cost, kLnSc));   // 256 * exp(-cost/eps)
        }
        *reinterpret_cast<unsigned int*>(&K[(size_t)r * NN + c0 + 4 * tc]) =
            pack8x4(e[0], e[1], e[2], e[3]);
    }
}

// -------------------------------- fused Sinkhorn pass: ONE read of K per iteration
// v = xform(rc) in registers; per 4-row group: dot -> u, then re-decode the SAME
// raw bytes (stashed per-thread in LDS, self-managed spill, no barrier needed for
// the stash since each thread reads only its own slots) for colacc += u_i * K_i.
// Block spans the full 8192-col row; lane owns 32 fixed cols. 32 rows/block,
// grid (256,1,3) = 3 blocks/CU. mode: 0 normal, 1 prepass (u=v=1), 2 final (no col).
__global__ __launch_bounds__(256, 3) void sk_pass(const unsigned char* __restrict__ K8,
                                                  const float* __restrict__ rc_in,
                                                  float* __restrict__ scratch,
                                                  float* __restrict__ u_arr,
                                                  int bands, int mode) {
    __shared__ uint4 ldsK[8][256];   // [slot][thread], lane-stride 16B: conflict-free
    __shared__ float part[2][16];
    const int z = blockIdx.z, b = blockIdx.x, t = threadIdx.x;
    const int lane = t & 63, w = t >> 6;
    const unsigned char* K = K8 + (size_t)z * NN * NN;
    const int cA = 2048 * w + 16 * lane;
    const int cB = cA + 1024;

    float vA[16], vB[16];
    if (mode == 1) {
#pragma unroll
        for (int j = 0; j < 16; j++) { vA[j] = 1.0f; vB[j] = 1.0f; }
    } else {
        const float* rc = rc_in + z * NN;
#pragma unroll
        for (int g4 = 0; g4 < 4; g4++) {
            float4 ra = *reinterpret_cast<const float4*>(rc + cA + 4 * g4);
            float4 rb = *reinterpret_cast<const float4*>(rc + cB + 4 * g4);
            vA[4 * g4 + 0] = xform(ra.x); vA[4 * g4 + 1] = xform(ra.y);
            vA[4 * g4 + 2] = xform(ra.z); vA[4 * g4 + 3] = xform(ra.w);
            vB[4 * g4 + 0] = xform(rb.x); vB[4 * g4 + 1] = xform(rb.y);
            vB[4 * g4 + 2] = xform(rb.z); vB[4 * g4 + 3] = xform(rb.w);
        }
    }

    float colA[16] = {}, colB[16] = {};
    const int r0 = b * 32;

    for (int g = 0; g < 8; g++) {
        const int rg = r0 + 4 * g;
        const int slot = g & 1;
        float p[4];
#pragma unroll
        for (int r = 0; r < 4; r++) {
            const unsigned char* rowp = K + (size_t)(rg + r) * NN;
            uint4 ka = *reinterpret_cast<const uint4*>(rowp + cA);
            uint4 kb = *reinterpret_cast<const uint4*>(rowp + cB);
            ldsK[r][t] = ka;
            ldsK[4 + r][t] = kb;
            float f[16];
            float pp = 0.f;
            cvt16(ka, f);
#pragma unroll
            for (int j = 0; j < 16; j++) pp = fmaf(f[j], vA[j], pp);
            cvt16(kb, f);
#pragma unroll
            for (int j = 0; j < 16; j++) pp = fmaf(f[j], vB[j], pp);
            p[r] = pp;
        }
#pragma unroll
        for (int off = 32; off > 0; off >>= 1) {
            p[0] += __shfl_xor(p[0], off); p[1] += __shfl_xor(p[1], off);
            p[2] += __shfl_xor(p[2], off); p[3] += __shfl_xor(p[3], off);
        }
        if (lane == 0) {
            part[slot][4 * w + 0] = p[0]; part[slot][4 * w + 1] = p[1];
            part[slot][4 * w + 2] = p[2]; part[slot][4 * w + 3] = p[3];
        }
        __syncthreads();
        if (t < 4) {
            const float s = part[slot][t] + part[slot][4 + t] +
                            part[slot][8 + t] + part[slot][12 + t];
            u_arr[z * NN + rg + t] = kMass / (s * kInvSc + kStab);
        }
        if (mode != 2) {
            float u4[4];
#pragma unroll
            for (int r = 0; r < 4; r++) {
                const float s = part[slot][r] + part[slot][4 + r] +
                                part[slot][8 + r] + part[slot][12 + r];
                u4[r] = (mode == 1)
                          ? 1.0f
                          : kMass * __builtin_amdgcn_rcpf(fmaf(s, kInvSc, kStab));
            }
#pragma unroll
            for (int r = 0; r < 4; r++) {
                uint4 ka = ldsK[r][t];
                uint4 kb = ldsK[4 + r][t];
                float f[16];
                cvt16(ka, f);
#pragma unroll
                for (int j = 0; j < 16; j++) colA[j] = fmaf(f[j], u4[r], colA[j]);
                cvt16(kb, f);
#pragma unroll
                for (int j = 0; j < 16; j++) colB[j] = fmaf(f[j], u4[r], colB[j]);
            }
        }
    }
    if (mode != 2) {
        float* sc = scratch + ((size_t)z * bands + (b & (bands - 1))) * NN;
        if (bands == 256) {   // one block per band: plain overwrite, no zeroing
#pragma unroll
            for (int g4 = 0; g4 < 4; g4++) {
                float4 a = {colA[4 * g4], colA[4 * g4 + 1],
                            colA[4 * g4 + 2], colA[4 * g4 + 3]};
                float4 bb = {colB[4 * g4], colB[4 * g4 + 1],
                             colB[4 * g4 + 2], colB[4 * g4 + 3]};
                *reinterpret_cast<float4*>(sc + cA + 4 * g4) = a;
                *reinterpret_cast<float4*>(sc + cB + 4 * g4) = bb;
            }
        } else {              // fallback: shared bands, atomic accumulate
#pragma unroll
            for (int j = 0; j < 16; j++) {
                atomicAdd(sc + cA + j, colA[j]);
                atomicAdd(sc + cB + j, colB[j]);
            }
        }
    }
}

// -------------------------------- rc_out[col] = sum over bands of scratch
__global__ __launch_bounds__(256) void sk_reduce(float* __restrict__ scratch,
                                                 float* __restrict__ rc_out,
                                                 int bands) {
    const int z = blockIdx.z;
    const int col = blockIdx.x * 256 + threadIdx.x;
    float* base = scratch + (size_t)z * bands * NN + col;
    float s = 0.f;
#pragma unroll 16
    for (int b = 0; b < bands; b++) s += base[(size_t)b * NN];
    if (bands != 256) {   // atomic fallback path: re-zero for next pass
        for (int b = 0; b < bands; b++) base[(size_t)b * NN] = 0.f;
    }
    rc_out[z * NN + col] = s;
}

// -------------------------------- w[z] = sum u_i K_ij v_j cost_ij, cost = -eps*ln(K)
__global__ __launch_bounds__(256) void sk_wsum(const unsigned char* __restrict__ K8,
                                               const float* __restrict__ rc_v,
                                               const float* __restrict__ u_arr,
                                               double* __restrict__ acc_out) {
    __shared__ float vs[10240];
    __shared__ double wred[4];
    const int t = threadIdx.x;
    const int z = blockIdx.z;
    const unsigned char* K = K8 + (size_t)z * NN * NN;
#pragma unroll
    for (int qq = 0; qq < 8; qq++) {
        const int j = 4 * t + 1024 * qq;
        float4 r = *reinterpret_cast<const float4*>(rc_v + z * NN + j);
        float4 g = {xform(r.x), xform(r.y), xform(r.z), xform(r.w)};
        *reinterpret_cast<float4*>(&vs[SIDX(j)]) = g;
    }
    __syncthreads();

    const int lane = t & 63, w = t >> 6;
    const int rbase = blockIdx.x * 32 + 8 * w;
    float pr[8] = {};
    const unsigned char* rp = K + (size_t)rbase * NN + 16 * lane;
    for (int s = 0; s < 8; s++) {
        const float* vp = &vs[20 * lane + 1280 * s];
        float vv[16];
#pragma unroll
        for (int g = 0; g < 4; g++) {
            float4 v4 = *reinterpret_cast<const float4*>(vp + 4 * g);
            vv[4 * g] = v4.x; vv[4 * g + 1] = v4.y;
            vv[4 * g + 2] = v4.z; vv[4 * g + 3] = v4.w;
        }
        const unsigned char* ps = rp + 1024 * s;
#pragma unroll
        for (int r = 0; r < 8; r++) {
            uint4 kk = *reinterpret_cast<const uint4*>(ps + (size_t)r * NN);
            float f[16];
            cvt16(kk, f);
            float a = pr[r];
#pragma unroll
            for (int j = 0; j < 16; j++)
                a = fmaf(f[j] * vv[j], __logf(fmaxf(f[j], 1e-30f) * kInvSc), a);
            pr[r] = a;
        }
    }
    double lacc = 0.0;
#pragma unroll
    for (int r = 0; r < 8; r++)
        lacc += (double)(u_arr[z * NN + rbase + r] * pr[r]);
    lacc *= (double)kInvSc;
    for (int off = 32; off > 0; off >>= 1) lacc += __shfl_down(lacc, off);
    if (lane == 0) wred[w] = lacc;
    __syncthreads();
    if (t == 0) {
        double total = -(double)kEps * (wred[0] + wred[1] + wred[2] + wred[3]);
        atomicAdd(&acc_out[z], total);
    }
}

// ------------------------------------------------- combine
__global__ void sk_combine(const double* __restrict__ acc, float* __restrict__ out) {
    if (threadIdx.x == 0)
        out[0] = (float)((acc[0] - 0.5 * acc[1] - 0.5 * acc[2]) / 8192.0);
}

extern "C" void kernel_launch(void* const* d_in, const int* in_sizes, int n_in,
                              void* d_out, int out_size, void* d_ws, size_t ws_size,
                              hipStream_t stream) {
    const float* src = (const float*)d_in[0];
    const float* tgt = (const float*)d_in[1];
    float* out = (float*)d_out;
    char* ws = (char*)d_ws;

    // workspace layout: K (192 MB) | scratch (bands*96KB) | rc0 | rc1 | u | wacc
    const size_t fixed = 3ull * NN * NN + 9ull * NN * sizeof(float) + 64;
    int bands = 256;
    while (bands > 16 && fixed + 3ull * bands * NN * sizeof(float) > ws_size)
        bands >>= 1;

    unsigned char* K8 = (unsigned char*)ws;
    float* scratch = (float*)(ws + 3ull * NN * NN);
    float* rc0   = scratch + (size_t)3 * bands * NN;
    float* rc1   = rc0 + 3 * NN;
    float* u_arr = rc1 + 3 * NN;
    double* wacc = (double*)(u_arr + 3 * NN);
    float* rcs[2] = {rc0, rc1};

    hipMemsetAsync(wacc, 0, 3 * sizeof(double), stream);
    if (bands != 256)   // atomic fallback needs zeroed scratch
        hipMemsetAsync(scratch, 0, 3ull * bands * NN * sizeof(float), stream);

    sk_build_k<<<dim3(128, 128, 3), 256, 0, stream>>>(src, tgt, K8);

    // prepass: rc_1 = 256 * K^T 1  (column sums)
    sk_pass<<<dim3(256, 1, 3), 256, 0, stream>>>(K8, rc0, scratch, u_arr, bands, 1);
    sk_reduce<<<dim3(32, 1, 3), 256, 0, stream>>>(scratch, rcs[1], bands);

    for (int it = 1; it <= 100; it++) {
        const int mode = (it == 100) ? 2 : 0;
        sk_pass<<<dim3(256, 1, 3), 256, 0, stream>>>(K8, rcs[it & 1], scratch,
                                                     u_arr, bands, mode);
        if (it < 100)
            sk_reduce<<<dim3(32, 1, 3), 256, 0, stream>>>(scratch,
                                                          rcs[(it + 1) & 1], bands);
    }
    // pass 100 read rcs[0] (= 256*K^T u_99): v_100 = xform(rcs[0]); u_100 in u_arr
    sk_wsum<<<dim3(256, 1, 3), 256, 0, stream>>>(K8, rcs[0], u_arr, wacc);
    sk_combine<<<1, 64, 0, stream>>>(wacc, out);
}